// Round 6
// baseline (52.534 us; speedup 1.0000x reference)
//
#include <hip/hip_runtime.h>

// Floyd-Steinberg halftoning, fused, 2-threads-per-tile (lane pair).
//
// R2-R5 lesson: the compiler always chunks loads to ~120 VGPRs, so per-thread
// MLP is capped; the only lever left is TLP. Here each 8x8 tile is owned by a
// lane PAIR (even lane: ch0+ch1, odd lane: ch2). Partial gray terms are
// exchanged with one __shfl_xor(.,1) per pixel; both lanes then compute
// g = own + recv (IEEE add commutes bit-exactly) and run the serial FS
// redundantly (free: pair shares the wave), each storing its own channels
// with its own zero-masks. 262144 threads = 4 waves/SIMD (2x R2), pinned by
// __launch_bounds__(256,4) (128-VGPR budget).
// Exact reference math: contract(off), (0.114*s0 + 0.587*s1) + 0.299*s2.

#define IMG_H 1024
#define IMG_W 1024
#define NCH   3

typedef float v4f __attribute__((ext_vector_type(4)));

__global__ __launch_bounds__(256, 4)
void fs_halftone_kernel(const float* __restrict__ in, float* __restrict__ out,
                        int n_imgs) {
#pragma clang fp contract(off)
    const int tiles_w = IMG_W / 8;                 // 128
    const int tiles_per_img = tiles_w * (IMG_H / 8);

    int gtid = blockIdx.x * blockDim.x + threadIdx.x;
    int tile = gtid >> 1;
    int role = gtid & 1;                           // 0: ch0+ch1, 1: ch2
    int b  = tile / tiles_per_img;
    if (b >= n_imgs) return;
    int t  = tile % tiles_per_img;
    int th = t / tiles_w;
    int tw = t % tiles_w;

    const size_t imgstride = (size_t)IMG_H * IMG_W;
    const size_t tile_off  = (size_t)(th * 8) * IMG_W + (size_t)(tw * 8);
    const float* base = in  + (size_t)b * NCH * imgstride + tile_off;
    float*      obase = out + (size_t)b * NCH * imgstride + tile_off;

    // ---- role-split loads ----
    // every lane: 16 float4 from its "primary" plane (A: ch0, B: ch2)
    const float* basep = base + (size_t)(role ? 2 : 0) * imgstride;
    v4f la[8][2];
#pragma unroll
    for (int r = 0; r < 8; ++r) {
        la[r][0] = *(const v4f*)(basep + (size_t)r * IMG_W);
        la[r][1] = *(const v4f*)(basep + (size_t)r * IMG_W + 4);
    }

    // partial gray p + own zero-masks
    float p[64];
    unsigned long long zma = 0ull, zmb = 0ull;  // A: zm0, zm1 ; B: zm2, unused

    if (!role) {
        v4f lb[8][2];                           // ch1 (even lanes only)
#pragma unroll
        for (int r = 0; r < 8; ++r) {
            lb[r][0] = *(const v4f*)(base + 1 * imgstride + (size_t)r * IMG_W);
            lb[r][1] = *(const v4f*)(base + 1 * imgstride + (size_t)r * IMG_W + 4);
        }
#pragma unroll
        for (int r = 0; r < 8; ++r) {
#pragma unroll
            for (int h = 0; h < 2; ++h) {
#pragma unroll
                for (int k = 0; k < 4; ++k) {
                    int idx = r * 8 + h * 4 + k;
                    float s0 = la[r][h][k] * 255.0f;
                    float s1 = lb[r][h][k] * 255.0f;
                    if (s0 == 0.0f) zma |= 1ull << idx;
                    if (s1 == 0.0f) zmb |= 1ull << idx;
                    p[idx] = (0.114f * s0) + (0.587f * s1);
                }
            }
        }
    } else {
#pragma unroll
        for (int r = 0; r < 8; ++r) {
#pragma unroll
            for (int h = 0; h < 2; ++h) {
#pragma unroll
                for (int k = 0; k < 4; ++k) {
                    int idx = r * 8 + h * 4 + k;
                    float s2 = la[r][h][k] * 255.0f;
                    if (s2 == 0.0f) zma |= 1ull << idx;
                    p[idx] = 0.299f * s2;
                }
            }
        }
    }

    // ---- pair exchange: g = own partial + partner partial (IEEE add
    //      commutes bit-exactly, so both lanes get the reference value) ----
    float g[64];
#pragma unroll
    for (int i = 0; i < 64; ++i) {
        float recv = __shfl_xor(p[i], 1);
        g[i] = p[i] + recv;
    }

    // ---- Floyd-Steinberg on the TRANSPOSED tile (both lanes, redundant).
    // FS row i == original column i; FS col j == original row j.
    float nrow[8];
#pragma unroll
    for (int j = 0; j < 8; ++j) nrow[j] = 0.0f;

    unsigned long long hbits = 0ull;  // bit (j*8+i): halftone==255 at orig (j,i)

#pragma unroll
    for (int i = 0; i < 8; ++i) {
        float errs[8];
        float er = 0.0f;
#pragma unroll
        for (int j = 0; j < 8; ++j) {
            float px  = g[j * 8 + i] + nrow[j];
            float old = px + er;
            bool  on  = old > 127.0f;
            float nw  = on ? 255.0f : 0.0f;
            float e   = old - nw;
            er = e * 0.4375f;                    // 7/16
            errs[j] = e;
            if (on) hbits |= 1ull << (j * 8 + i);
        }
#pragma unroll
        for (int j = 0; j < 8; ++j) {
            float en = (j < 7) ? errs[j + 1] : 0.0f;
            float ep = (j > 0) ? errs[j - 1] : 0.0f;
            nrow[j] = ((0.3125f * errs[j]) + (0.1875f * en)) + (0.0625f * ep);
        }
    }

    // ---- role-split stores: out = (scaled==0) ? 0 : ht/255 ----
    if (!role) {
#pragma unroll
        for (int ch = 0; ch < 2; ++ch) {
            unsigned long long zm = (ch == 0) ? zma : zmb;
#pragma unroll
            for (int r = 0; r < 8; ++r) {
                v4f v0, v1;
#pragma unroll
                for (int c = 0; c < 8; ++c) {
                    int idx = r * 8 + c;
                    bool on = (hbits >> idx) & 1ull;
                    bool z  = (zm    >> idx) & 1ull;
                    float val = (on && !z) ? 1.0f : 0.0f;
                    if (c < 4) v0[c] = val; else v1[c - 4] = val;
                }
                *(v4f*)(obase + ch * imgstride + (size_t)r * IMG_W)     = v0;
                *(v4f*)(obase + ch * imgstride + (size_t)r * IMG_W + 4) = v1;
            }
        }
    } else {
#pragma unroll
        for (int r = 0; r < 8; ++r) {
            v4f v0, v1;
#pragma unroll
            for (int c = 0; c < 8; ++c) {
                int idx = r * 8 + c;
                bool on = (hbits >> idx) & 1ull;
                bool z  = (zma   >> idx) & 1ull;
                float val = (on && !z) ? 1.0f : 0.0f;
                if (c < 4) v0[c] = val; else v1[c - 4] = val;
            }
            *(v4f*)(obase + 2 * imgstride + (size_t)r * IMG_W)     = v0;
            *(v4f*)(obase + 2 * imgstride + (size_t)r * IMG_W + 4) = v1;
        }
    }
}

extern "C" void kernel_launch(void* const* d_in, const int* in_sizes, int n_in,
                              void* d_out, int out_size, void* d_ws, size_t ws_size,
                              hipStream_t stream) {
    const float* in  = (const float*)d_in[0];
    float*       out = (float*)d_out;

    int n_imgs = in_sizes[0] / (NCH * IMG_H * IMG_W);  // 8
    int total_threads = 2 * n_imgs * (IMG_H / 8) * (IMG_W / 8);  // 2 per tile
    int block = 256;
    int grid = (total_threads + block - 1) / block;
    fs_halftone_kernel<<<grid, block, 0, stream>>>(in, out, n_imgs);
}

// Round 7
// 39.421 us; speedup vs baseline: 1.3326x; 1.3326x over previous
//
#include <hip/hip_runtime.h>

// Floyd-Steinberg halftoning, fused, 2-threads-per-tile POSITION split.
//
// Lane pair owns one 8x8 tile: even lane = columns 0-3, odd lane = columns 4-7.
// Each lane loads ALL 3 channels of its 16B column slab -> every load/store
// instruction is 64 lanes x 16B = 1KB contiguous within one plane (full cache
// lines). Each lane computes gray + its own zero-masks locally (exact ref
// order, contract off); one __shfl_xor(.,1) per gray value assembles the full
// tile in both lanes; FS runs redundantly (pair shares the wave, so it's
// free); each lane stores only its own columns.
//
// 262144 threads = 4 waves/SIMD capacity. __launch_bounds__(256,2): R6 showed
// forcing (256,4) makes the allocator pick 64 VGPRs and SPILL g[64] to
// scratch (WRITE_SIZE 98->153MB, 42->52us). (256,2) gave 120 regs, no spill.

#define IMG_H 1024
#define IMG_W 1024
#define NCH   3

typedef float v4f __attribute__((ext_vector_type(4)));

__global__ __launch_bounds__(256, 2)
void fs_halftone_kernel(const float* __restrict__ in, float* __restrict__ out,
                        int n_imgs) {
#pragma clang fp contract(off)
    const int tiles_w = IMG_W / 8;                 // 128
    const int tiles_per_img = tiles_w * (IMG_H / 8);

    int gtid = blockIdx.x * blockDim.x + threadIdx.x;
    int tile = gtid >> 1;
    int h    = gtid & 1;                           // column half: 0 -> cols 0-3, 1 -> cols 4-7
    int b  = tile / tiles_per_img;
    if (b >= n_imgs) return;
    int t  = tile % tiles_per_img;
    int th = t / tiles_w;
    int tw = t % tiles_w;

    const size_t imgstride = (size_t)IMG_H * IMG_W;
    const size_t slab_off  = (size_t)(th * 8) * IMG_W + (size_t)(tw * 8) + (size_t)(h * 4);
    const float* base = in  + (size_t)b * NCH * imgstride + slab_off;
    float*      obase = out + (size_t)b * NCH * imgstride + slab_off;

    // ---- loads: 3 channels x 8 rows x one float4 (own column slab) ----
    v4f l0[8], l1[8], l2[8];
#pragma unroll
    for (int r = 0; r < 8; ++r) l0[r] = *(const v4f*)(base + 0 * imgstride + (size_t)r * IMG_W);
#pragma unroll
    for (int r = 0; r < 8; ++r) l1[r] = *(const v4f*)(base + 1 * imgstride + (size_t)r * IMG_W);
#pragma unroll
    for (int r = 0; r < 8; ++r) l2[r] = *(const v4f*)(base + 2 * imgstride + (size_t)r * IMG_W);

    // ---- gray (full, exact reference order) + own zero-masks, own 32 px ----
    float p[32];                       // own-position gray, index r*4+k
    unsigned int zm0 = 0u, zm1 = 0u, zm2 = 0u;   // bits r*4+k
#pragma unroll
    for (int r = 0; r < 8; ++r) {
#pragma unroll
        for (int k = 0; k < 4; ++k) {
            int idx = r * 4 + k;
            float s0 = l0[r][k] * 255.0f;
            float s1 = l1[r][k] * 255.0f;
            float s2 = l2[r][k] * 255.0f;
            if (s0 == 0.0f) zm0 |= 1u << idx;
            if (s1 == 0.0f) zm1 |= 1u << idx;
            if (s2 == 0.0f) zm2 |= 1u << idx;
            p[idx] = ((0.114f * s0) + (0.587f * s1)) + (0.299f * s2);
        }
    }

    // ---- pair exchange -> full-tile gray in both lanes (compile-time idx) ----
    float g[64];
#pragma unroll
    for (int r = 0; r < 8; ++r) {
#pragma unroll
        for (int k = 0; k < 4; ++k) {
            float o = p[r * 4 + k];
            float x = __shfl_xor(o, 1);
            g[r * 8 + k]     = (h == 0) ? o : x;   // cols 0-3
            g[r * 8 + 4 + k] = (h == 0) ? x : o;   // cols 4-7
        }
    }

    // ---- Floyd-Steinberg on the TRANSPOSED tile (redundant in both lanes).
    // FS row i == original column i; FS col j == original row j.
    float nrow[8];
#pragma unroll
    for (int j = 0; j < 8; ++j) nrow[j] = 0.0f;

    unsigned long long hbits = 0ull;  // bit (j*8+i): halftone==255 at orig (j,i)

#pragma unroll
    for (int i = 0; i < 8; ++i) {
        float errs[8];
        float er = 0.0f;
#pragma unroll
        for (int j = 0; j < 8; ++j) {
            float px  = g[j * 8 + i] + nrow[j];
            float old = px + er;
            bool  on  = old > 127.0f;
            float nw  = on ? 255.0f : 0.0f;
            float e   = old - nw;
            er = e * 0.4375f;                    // 7/16
            errs[j] = e;
            if (on) hbits |= 1ull << (j * 8 + i);
        }
#pragma unroll
        for (int j = 0; j < 8; ++j) {
            float en = (j < 7) ? errs[j + 1] : 0.0f;
            float ep = (j > 0) ? errs[j - 1] : 0.0f;
            nrow[j] = ((0.3125f * errs[j]) + (0.1875f * en)) + (0.0625f * ep);
        }
    }

    // ---- stores: own columns only, all 3 planes; 1KB contiguous per instr ----
    int hs = h << 2;                   // column offset of own half within the tile
#pragma unroll
    for (int ch = 0; ch < 3; ++ch) {
        unsigned int zm = (ch == 0) ? zm0 : ((ch == 1) ? zm1 : zm2);
#pragma unroll
        for (int r = 0; r < 8; ++r) {
            v4f v;
#pragma unroll
            for (int k = 0; k < 4; ++k) {
                bool on = (hbits >> (r * 8 + hs + k)) & 1ull;
                bool z  = (zm    >> (r * 4 + k)) & 1u;
                v[k] = (on && !z) ? 1.0f : 0.0f;
            }
            *(v4f*)(obase + ch * imgstride + (size_t)r * IMG_W) = v;
        }
    }
}

extern "C" void kernel_launch(void* const* d_in, const int* in_sizes, int n_in,
                              void* d_out, int out_size, void* d_ws, size_t ws_size,
                              hipStream_t stream) {
    const float* in  = (const float*)d_in[0];
    float*       out = (float*)d_out;

    int n_imgs = in_sizes[0] / (NCH * IMG_H * IMG_W);  // 8
    int total_threads = 2 * n_imgs * (IMG_H / 8) * (IMG_W / 8);  // 2 per tile
    int block = 256;
    int grid = (total_threads + block - 1) / block;
    fs_halftone_kernel<<<grid, block, 0, stream>>>(in, out, n_imgs);
}

// Round 8
// 37.700 us; speedup vs baseline: 1.3935x; 1.0457x over previous
//
#include <hip/hip_runtime.h>

// Floyd-Steinberg halftoning, fused, 4-threads-per-tile position split.
//
// Each 8x8 tile is owned by a lane QUAD; lane q' owns original columns
// {2q', 2q'+1} (a float2 slab), all 3 channels. Gray + zero-masks computed
// locally (exact ref order, contract off) into p[16] -- there is NO g[64]
// (R6: g[64] + tight launch bounds => scratch spill). During FS, row i
// (original column i) fetches its 8 column values on demand via
// __shfl(p[j*2+(i&1)], (lane&~3)|(i>>1)) -- all p indices compile-time, so
// everything stays in VGPRs. FS runs redundantly in all 4 lanes (free at
// wave level); each lane stores only its own 2 columns.
//
// Grid: 4*131072 = 524288 threads = 2048 blocks = 8 blocks/CU.
// __launch_bounds__(256,6): ~84-VGPR cap -- 6 waves/SIMD (1.5x R7's 4)
// with low spill risk (live set ~45 regs by construction).

#define IMG_H 1024
#define IMG_W 1024
#define NCH   3

typedef float v2f __attribute__((ext_vector_type(2)));

__global__ __launch_bounds__(256, 6)
void fs_halftone_kernel(const float* __restrict__ in, float* __restrict__ out,
                        int n_imgs) {
#pragma clang fp contract(off)
    const int tiles_w = IMG_W / 8;                 // 128
    const int tiles_per_img = tiles_w * (IMG_H / 8);

    int gtid = blockIdx.x * blockDim.x + threadIdx.x;
    int tile = gtid >> 2;
    int q    = gtid & 3;                           // quad index: owns cols {2q, 2q+1}
    int lane = threadIdx.x & 63;
    int b  = tile / tiles_per_img;
    if (b >= n_imgs) return;
    int t  = tile % tiles_per_img;
    int th = t / tiles_w;
    int tw = t % tiles_w;

    const size_t imgstride = (size_t)IMG_H * IMG_W;
    const size_t slab_off  = (size_t)(th * 8) * IMG_W + (size_t)(tw * 8) + (size_t)(q * 2);
    const float* base = in  + (size_t)b * NCH * imgstride + slab_off;
    float*      obase = out + (size_t)b * NCH * imgstride + slab_off;

    // ---- per-channel loads (float2/lane, 512B contiguous per wave instr),
    //      accumulated into p in exact reference order ----
    float p[16];                                   // own gray, idx r*2+k
    unsigned int zm0 = 0u, zm1 = 0u, zm2 = 0u;     // bits r*2+k

    {
        v2f l[8];
#pragma unroll
        for (int r = 0; r < 8; ++r) l[r] = *(const v2f*)(base + 0 * imgstride + (size_t)r * IMG_W);
#pragma unroll
        for (int r = 0; r < 8; ++r)
#pragma unroll
            for (int k = 0; k < 2; ++k) {
                int idx = r * 2 + k;
                float s0 = l[r][k] * 255.0f;
                if (s0 == 0.0f) zm0 |= 1u << idx;
                p[idx] = 0.114f * s0;
            }
    }
    {
        v2f l[8];
#pragma unroll
        for (int r = 0; r < 8; ++r) l[r] = *(const v2f*)(base + 1 * imgstride + (size_t)r * IMG_W);
#pragma unroll
        for (int r = 0; r < 8; ++r)
#pragma unroll
            for (int k = 0; k < 2; ++k) {
                int idx = r * 2 + k;
                float s1 = l[r][k] * 255.0f;
                if (s1 == 0.0f) zm1 |= 1u << idx;
                p[idx] = p[idx] + (0.587f * s1);   // (0.114*s0) + (0.587*s1)
            }
    }
    {
        v2f l[8];
#pragma unroll
        for (int r = 0; r < 8; ++r) l[r] = *(const v2f*)(base + 2 * imgstride + (size_t)r * IMG_W);
#pragma unroll
        for (int r = 0; r < 8; ++r)
#pragma unroll
            for (int k = 0; k < 2; ++k) {
                int idx = r * 2 + k;
                float s2 = l[r][k] * 255.0f;
                if (s2 == 0.0f) zm2 |= 1u << idx;
                p[idx] = p[idx] + (0.299f * s2);   // ((...)+0.299*s2), exact ref tree
            }
    }

    // ---- Floyd-Steinberg on the TRANSPOSED tile (redundant across the quad).
    // FS row i == original column i, owned by quad-lane i>>1, element j*2+(i&1).
    float nrow[8];
#pragma unroll
    for (int j = 0; j < 8; ++j) nrow[j] = 0.0f;

    unsigned long long hbits = 0ull;  // bit (j*8+i): halftone==255 at orig (j,i)

#pragma unroll
    for (int i = 0; i < 8; ++i) {
        const int oq = i >> 1, ip = i & 1;         // compile-time
        // broadcast column i from its owner lane
        float cv[8];
#pragma unroll
        for (int j = 0; j < 8; ++j)
            cv[j] = __shfl(p[j * 2 + ip], (lane & ~3) | oq);

        float errs[8];
        float er = 0.0f;
#pragma unroll
        for (int j = 0; j < 8; ++j) {
            float px  = cv[j] + nrow[j];
            float old = px + er;
            bool  on  = old > 127.0f;
            float nw  = on ? 255.0f : 0.0f;
            float e   = old - nw;
            er = e * 0.4375f;                      // 7/16
            errs[j] = e;
            if (on) hbits |= 1ull << (j * 8 + i);
        }
#pragma unroll
        for (int j = 0; j < 8; ++j) {
            float en = (j < 7) ? errs[j + 1] : 0.0f;
            float ep = (j > 0) ? errs[j - 1] : 0.0f;
            nrow[j] = ((0.3125f * errs[j]) + (0.1875f * en)) + (0.0625f * ep);
        }
    }

    // ---- stores: own 2 columns, all 3 planes ----
    const int c0 = q * 2;
#pragma unroll
    for (int ch = 0; ch < 3; ++ch) {
        unsigned int zm = (ch == 0) ? zm0 : ((ch == 1) ? zm1 : zm2);
#pragma unroll
        for (int r = 0; r < 8; ++r) {
            v2f v;
#pragma unroll
            for (int k = 0; k < 2; ++k) {
                bool on = (hbits >> (r * 8 + c0 + k)) & 1ull;
                bool z  = (zm    >> (r * 2 + k)) & 1u;
                v[k] = (on && !z) ? 1.0f : 0.0f;
            }
            *(v2f*)(obase + ch * imgstride + (size_t)r * IMG_W) = v;
        }
    }
}

extern "C" void kernel_launch(void* const* d_in, const int* in_sizes, int n_in,
                              void* d_out, int out_size, void* d_ws, size_t ws_size,
                              hipStream_t stream) {
    const float* in  = (const float*)d_in[0];
    float*       out = (float*)d_out;

    int n_imgs = in_sizes[0] / (NCH * IMG_H * IMG_W);  // 8
    int total_threads = 4 * n_imgs * (IMG_H / 8) * (IMG_W / 8);  // 4 per tile
    int block = 256;
    int grid = (total_threads + block - 1) / block;
    fs_halftone_kernel<<<grid, block, 0, stream>>>(in, out, n_imgs);
}